// Round 1
// baseline (519.395 us; speedup 1.0000x reference)
//
#include <hip/hip_runtime.h>
#include <hip/hip_bf16.h>

#define NTOT   65536
#define CDIM   128
#define NE     1048576
#define NGRAPH 64
#define NNODE  1024
#define NLAYER 4
#define SLOPE  0.01f

typedef __attribute__((ext_vector_type(8))) short short8;   // 8 bf16 (4 VGPRs) MFMA frag
typedef __attribute__((ext_vector_type(4))) float f32x4;    // MFMA accum frag
typedef unsigned int u32;
typedef unsigned short u16;

__device__ __forceinline__ float bf2f(u32 v){ return __uint_as_float(v << 16); }
__device__ __forceinline__ u16 f2bf(float f){
    u32 u = __float_as_uint(f);
    u += 0x7fffu + ((u >> 16) & 1u);      // round-to-nearest-even
    return (u16)(u >> 16);
}
__device__ __forceinline__ float lk(float x){ return x >= 0.f ? x : SLOPE * x; }

// ---------------- cast x (f32) -> h (bf16) ----------------
__global__ void k_cast_x(const float* __restrict__ x, u16* __restrict__ h){
    int i = blockIdx.x * 256 + threadIdx.x;          // 8 elems per thread
    const float4* x4 = (const float4*)x;
    float4 a = x4[i * 2], b = x4[i * 2 + 1];
    u32 r0 = (u32)f2bf(a.x) | ((u32)f2bf(a.y) << 16);
    u32 r1 = (u32)f2bf(a.z) | ((u32)f2bf(a.w) << 16);
    u32 r2 = (u32)f2bf(b.x) | ((u32)f2bf(b.y) << 16);
    u32 r3 = (u32)f2bf(b.z) | ((u32)f2bf(b.w) << 16);
    ((uint4*)h)[i] = make_uint4(r0, r1, r2, r3);
}

// ------- convert + transpose weights: Wt[l][g][c][k] = (bf16) W_g[l][k][c] -------
__global__ void k_conv_w(const float* __restrict__ W1, const float* __restrict__ W2,
                         u16* __restrict__ Wt){
    int idx = blockIdx.x * 256 + threadIdx.x;        // L*2*128*128 = 131072
    int k = idx & 127;
    int c = (idx >> 7) & 127;
    int g = (idx >> 14) & 1;
    int l = idx >> 15;
    const float* W = g ? W2 : W1;
    Wt[idx] = f2bf(W[(l * 128 + k) * 128 + c]);
}

// ---------------- CSR build ----------------
__global__ void k_hist(const int* __restrict__ dst, int* __restrict__ deg){
    int e = blockIdx.x * 256 + threadIdx.x;
    atomicAdd(&deg[dst[e]], 1);
}

__global__ void k_scan(int* __restrict__ cursor /* deg in, cursor out */,
                       int* __restrict__ row_start){
    __shared__ int part[1024];
    int tid = threadIdx.x;
    int base = tid * 64;
    int s = 0;
    for (int i = 0; i < 64; ++i) s += cursor[base + i];
    part[tid] = s;
    __syncthreads();
    for (int off = 1; off < 1024; off <<= 1){
        int v = (tid >= off) ? part[tid - off] : 0;
        __syncthreads();
        part[tid] += v;
        __syncthreads();
    }
    int run = part[tid] - s;                          // exclusive prefix
    for (int i = 0; i < 64; ++i){
        int d = cursor[base + i];
        row_start[base + i] = run;
        cursor[base + i] = run;
        run += d;
    }
    if (tid == 1023) row_start[NTOT] = run;
}

__global__ void k_fill(const int* __restrict__ src, const int* __restrict__ dst,
                       int* __restrict__ cursor, int* __restrict__ csr){
    int e = blockIdx.x * 256 + threadIdx.x;
    int d = dst[e];
    int p = atomicAdd(&cursor[d], 1);
    csr[p] = src[e];
}

// ---------------- aggregation: t[n] = h[n] + sum_{e: dst=n} h[src_e] ----------------
__global__ void k_agg(const u16* __restrict__ h, const int* __restrict__ row_start,
                      const int* __restrict__ csr, u16* __restrict__ t){
    int tid = threadIdx.x;
    int lane16 = tid & 15;
    int n = blockIdx.x * 16 + (tid >> 4);
    const uint4* h4 = (const uint4*)h;

    float acc[8];
    uint4 v = h4[n * 16 + lane16];
    acc[0] = bf2f(v.x & 0xffffu); acc[1] = bf2f(v.x >> 16);
    acc[2] = bf2f(v.y & 0xffffu); acc[3] = bf2f(v.y >> 16);
    acc[4] = bf2f(v.z & 0xffffu); acc[5] = bf2f(v.z >> 16);
    acc[6] = bf2f(v.w & 0xffffu); acc[7] = bf2f(v.w >> 16);

    int s = row_start[n], e = row_start[n + 1];
    for (int p = s; p < e; ++p){
        int sn = csr[p];
        uint4 w = h4[sn * 16 + lane16];
        acc[0] += bf2f(w.x & 0xffffu); acc[1] += bf2f(w.x >> 16);
        acc[2] += bf2f(w.y & 0xffffu); acc[3] += bf2f(w.y >> 16);
        acc[4] += bf2f(w.z & 0xffffu); acc[5] += bf2f(w.z >> 16);
        acc[6] += bf2f(w.w & 0xffffu); acc[7] += bf2f(w.w >> 16);
    }
    u32 r0 = (u32)f2bf(acc[0]) | ((u32)f2bf(acc[1]) << 16);
    u32 r1 = (u32)f2bf(acc[2]) | ((u32)f2bf(acc[3]) << 16);
    u32 r2 = (u32)f2bf(acc[4]) | ((u32)f2bf(acc[5]) << 16);
    u32 r3 = (u32)f2bf(acc[6]) | ((u32)f2bf(acc[7]) << 16);
    ((uint4*)t)[n * 16 + lane16] = make_uint4(r0, r1, r2, r3);
}

// ---------------- fused 2-GEMM MLP: h = act(leaky(t@W1+b1)@W2+b2) ----------------
// block = 256 (4 waves), 64 rows/block; wave computes 16 rows x 128 cols.
__global__ __launch_bounds__(256) void k_mlp(const u16* __restrict__ t,
                                             const u16* __restrict__ Wt,
                                             const float* __restrict__ b1,
                                             const float* __restrict__ b2,
                                             u16* __restrict__ h,
                                             int layer, int act){
    __shared__ __align__(16) u16 u_lds[4][16][136];   // padded stride: 272B rows
    int tid  = threadIdx.x;
    int wid  = tid >> 6, lane = tid & 63;
    int l16  = lane & 15, kg = lane >> 4;
    int rbase = blockIdx.x * 64 + wid * 16;
    const u16* Wt1 = Wt + (size_t)(layer * 2) * 16384;
    const u16* Wt2 = Wt1 + 16384;

    // ---- GEMM1: U = T @ W1 ----
    f32x4 acc[8];
    for (int f = 0; f < 8; ++f) acc[f] = (f32x4){0.f, 0.f, 0.f, 0.f};
    int arow = rbase + l16;
    for (int ks = 0; ks < 4; ++ks){
        int k0 = ks * 32 + kg * 8;
        short8 afrag = *(const short8*)(t + (size_t)arow * 128 + k0);
        for (int f = 0; f < 8; ++f){
            short8 bfrag = *(const short8*)(Wt1 + (f * 16 + l16) * 128 + k0);
            acc[f] = __builtin_amdgcn_mfma_f32_16x16x32_bf16(afrag, bfrag, acc[f], 0, 0, 0);
        }
    }
    // epilogue 1: +b1, leaky, to LDS (A-operand layout for GEMM2)
    for (int f = 0; f < 8; ++f){
        int col = f * 16 + l16;
        float bv = b1[layer * 128 + col];
        for (int j = 0; j < 4; ++j){
            float v = lk(acc[f][j] + bv);
            u_lds[wid][kg * 4 + j][col] = f2bf(v);
        }
    }
    __syncthreads();

    // ---- GEMM2: H = U @ W2 ----
    f32x4 acc2[8];
    for (int f = 0; f < 8; ++f) acc2[f] = (f32x4){0.f, 0.f, 0.f, 0.f};
    for (int ks = 0; ks < 4; ++ks){
        int k0 = ks * 32 + kg * 8;
        short8 afrag = *(const short8*)(&u_lds[wid][l16][k0]);
        for (int f = 0; f < 8; ++f){
            short8 bfrag = *(const short8*)(Wt2 + (f * 16 + l16) * 128 + k0);
            acc2[f] = __builtin_amdgcn_mfma_f32_16x16x32_bf16(afrag, bfrag, acc2[f], 0, 0, 0);
        }
    }
    for (int f = 0; f < 8; ++f){
        int col = f * 16 + l16;
        float bv = b2[layer * 128 + col];
        for (int j = 0; j < 4; ++j){
            float v = acc2[f][j] + bv;
            if (act) v = lk(v);
            h[(size_t)(rbase + kg * 4 + j) * 128 + col] = f2bf(v);
        }
    }
}

// ---------------- FC1: y[n] = sum_c leaky(h[n][c]) * fc1_w[c] + fc1_b ----------------
__global__ void k_fc1(const u16* __restrict__ h, const float* __restrict__ fc1_w,
                      const float* __restrict__ fc1_b, float* __restrict__ y){
    int tid = threadIdx.x;
    int lane = tid & 63, wid = tid >> 6;
    int n = blockIdx.x * 4 + wid;
    u32 v = *(const u32*)(h + (size_t)n * 128 + lane * 2);
    float2 w = *(const float2*)(fc1_w + lane * 2);
    float s = lk(bf2f(v & 0xffffu)) * w.x + lk(bf2f(v >> 16)) * w.y;
    for (int off = 32; off; off >>= 1) s += __shfl_xor(s, off, 64);
    if (lane == 0) y[n] = s + fc1_b[0];
}

// ---------------- FC2 + log_softmax ----------------
__global__ void k_fc2(const float* __restrict__ y, const float* __restrict__ fc2_w,
                      const float* __restrict__ fc2_b, float* __restrict__ out){
    int b = blockIdx.x, tid = threadIdx.x;
    float a0 = 0.f, a1 = 0.f;
    for (int j = tid; j < 1024; j += 256){
        float v = lk(y[b * 1024 + j]);
        a0 += v * fc2_w[j];
        a1 += v * fc2_w[1024 + j];
    }
    for (int off = 32; off; off >>= 1){
        a0 += __shfl_xor(a0, off, 64);
        a1 += __shfl_xor(a1, off, 64);
    }
    __shared__ float s0[4], s1[4];
    int wid = tid >> 6, lane = tid & 63;
    if (lane == 0){ s0[wid] = a0; s1[wid] = a1; }
    __syncthreads();
    if (tid == 0){
        float l0 = s0[0] + s0[1] + s0[2] + s0[3] + fc2_b[0];
        float l1 = s1[0] + s1[1] + s1[2] + s1[3] + fc2_b[1];
        float m = fmaxf(l0, l1);
        float lse = m + logf(expf(l0 - m) + expf(l1 - m));
        out[b * 2 + 0] = l0 - lse;
        out[b * 2 + 1] = l1 - lse;
    }
}

extern "C" void kernel_launch(void* const* d_in, const int* in_sizes, int n_in,
                              void* d_out, int out_size, void* d_ws, size_t ws_size,
                              hipStream_t stream){
    (void)in_sizes; (void)n_in; (void)out_size; (void)ws_size;
    const float* x     = (const float*)d_in[0];
    const float* W1    = (const float*)d_in[1];
    const float* b1    = (const float*)d_in[2];
    const float* W2    = (const float*)d_in[3];
    const float* b2    = (const float*)d_in[4];
    const float* fc1_w = (const float*)d_in[5];
    const float* fc1_b = (const float*)d_in[6];
    const float* fc2_w = (const float*)d_in[7];
    const float* fc2_b = (const float*)d_in[8];
    const int*   edges = (const int*)d_in[9];
    const int*   esrc  = edges;
    const int*   edst  = edges + NE;

    char* w = (char*)d_ws;
    u16* h  = (u16*)w;            w += (size_t)NTOT * CDIM * 2;        // 16 MB
    u16* t  = (u16*)w;            w += (size_t)NTOT * CDIM * 2;        // 16 MB
    u16* Wt = (u16*)w;            w += (size_t)NLAYER * 2 * CDIM * CDIM * 2; // 256 KB
    float* y = (float*)w;         w += (size_t)NTOT * 4;               // 256 KB
    int* row_start = (int*)w;     w += (size_t)(NTOT + 4) * 4;
    int* cursor    = (int*)w;     w += (size_t)NTOT * 4;
    int* csr       = (int*)w;     w += (size_t)NE * 4;                 // 4 MB

    hipMemsetAsync(cursor, 0, (size_t)NTOT * 4, stream);
    k_cast_x<<<4096, 256, 0, stream>>>(x, h);
    k_conv_w<<<512, 256, 0, stream>>>(W1, W2, Wt);
    k_hist  <<<4096, 256, 0, stream>>>(edst, cursor);
    k_scan  <<<1, 1024, 0, stream>>>(cursor, row_start);
    k_fill  <<<4096, 256, 0, stream>>>(esrc, edst, cursor, csr);

    for (int l = 0; l < NLAYER; ++l){
        k_agg<<<4096, 256, 0, stream>>>(h, row_start, csr, t);
        k_mlp<<<1024, 256, 0, stream>>>(t, Wt, b1, b2, h, l, (l < NLAYER - 1) ? 1 : 0);
    }
    k_fc1<<<16384, 256, 0, stream>>>(h, fc1_w, fc1_b, y);
    k_fc2<<<NGRAPH, 256, 0, stream>>>(y, fc2_w, fc2_b, (float*)d_out);
}

// Round 2
// 445.315 us; speedup vs baseline: 1.1664x; 1.1664x over previous
//
#include <hip/hip_runtime.h>
#include <hip/hip_bf16.h>

#define NTOT   65536
#define CDIM   128
#define NE     1048576
#define NGRAPH 64
#define NNODE  1024
#define NLAYER 4
#define SLOPE  0.01f
#define PAD    64

typedef __attribute__((ext_vector_type(8))) short short8;   // 8 bf16 (4 VGPRs) MFMA frag
typedef __attribute__((ext_vector_type(4))) float f32x4;    // MFMA accum frag
typedef unsigned int u32;
typedef unsigned short u16;

__device__ __forceinline__ float bf2f(u32 v){ return __uint_as_float(v << 16); }
__device__ __forceinline__ u16 f2bf(float f){
    u32 u = __float_as_uint(f);
    u += 0x7fffu + ((u >> 16) & 1u);      // round-to-nearest-even
    return (u16)(u >> 16);
}
__device__ __forceinline__ float lk(float x){ return x >= 0.f ? x : SLOPE * x; }

// ---------------- cast x (f32) -> h (bf16) ----------------
__global__ void k_cast_x(const float* __restrict__ x, u16* __restrict__ h){
    int i = blockIdx.x * 256 + threadIdx.x;          // 8 elems per thread
    const float4* x4 = (const float4*)x;
    float4 a = x4[i * 2], b = x4[i * 2 + 1];
    u32 r0 = (u32)f2bf(a.x) | ((u32)f2bf(a.y) << 16);
    u32 r1 = (u32)f2bf(a.z) | ((u32)f2bf(a.w) << 16);
    u32 r2 = (u32)f2bf(b.x) | ((u32)f2bf(b.y) << 16);
    u32 r3 = (u32)f2bf(b.z) | ((u32)f2bf(b.w) << 16);
    ((uint4*)h)[i] = make_uint4(r0, r1, r2, r3);
}

// ------- convert + transpose weights: Wt[l][g][c][k] = (bf16) W_g[l][k][c] -------
__global__ void k_conv_w(const float* __restrict__ W1, const float* __restrict__ W2,
                         u16* __restrict__ Wt){
    int idx = blockIdx.x * 256 + threadIdx.x;        // L*2*128*128 = 131072
    int k = idx & 127;
    int c = (idx >> 7) & 127;
    int g = (idx >> 14) & 1;
    int l = idx >> 15;
    const float* W = g ? W2 : W1;
    Wt[idx] = f2bf(W[(l * 128 + k) * 128 + c]);
}

// ------- single-pass padded CSR: cnt[d]++ gives rank AND final degree -------
__global__ void k_fillp(const int* __restrict__ src, const int* __restrict__ dst,
                        int* __restrict__ cnt, u16* __restrict__ csrp){
    int e0 = (blockIdx.x * 256 + threadIdx.x) * 4;
    int4 d4 = *(const int4*)(dst + e0);
    int4 s4 = *(const int4*)(src + e0);
    int p;
    p = atomicAdd(&cnt[d4.x], 1); if (p < PAD) csrp[d4.x * PAD + p] = (u16)s4.x;
    p = atomicAdd(&cnt[d4.y], 1); if (p < PAD) csrp[d4.y * PAD + p] = (u16)s4.y;
    p = atomicAdd(&cnt[d4.z], 1); if (p < PAD) csrp[d4.z * PAD + p] = (u16)s4.z;
    p = atomicAdd(&cnt[d4.w], 1); if (p < PAD) csrp[d4.w * PAD + p] = (u16)s4.w;
}

// ---------------- aggregation: t[n] = h[n] + sum_{e: dst=n} h[src_e] ----------------
__global__ void k_agg(const u16* __restrict__ h, const int* __restrict__ cnt,
                      const u16* __restrict__ csrp, u16* __restrict__ t){
    int tid = threadIdx.x;
    int lane16 = tid & 15;
    int n = blockIdx.x * 16 + (tid >> 4);
    const uint4* h4 = (const uint4*)h;

    float acc[8];
    uint4 v = h4[n * 16 + lane16];
    acc[0] = bf2f(v.x & 0xffffu); acc[1] = bf2f(v.x >> 16);
    acc[2] = bf2f(v.y & 0xffffu); acc[3] = bf2f(v.y >> 16);
    acc[4] = bf2f(v.z & 0xffffu); acc[5] = bf2f(v.z >> 16);
    acc[6] = bf2f(v.w & 0xffffu); acc[7] = bf2f(v.w >> 16);

    int e = min(cnt[n], PAD);
    const u16* row = csrp + (size_t)n * PAD;
    for (int p = 0; p < e; ++p){
        int sn = row[p];
        uint4 w = h4[sn * 16 + lane16];
        acc[0] += bf2f(w.x & 0xffffu); acc[1] += bf2f(w.x >> 16);
        acc[2] += bf2f(w.y & 0xffffu); acc[3] += bf2f(w.y >> 16);
        acc[4] += bf2f(w.z & 0xffffu); acc[5] += bf2f(w.z >> 16);
        acc[6] += bf2f(w.w & 0xffffu); acc[7] += bf2f(w.w >> 16);
    }
    u32 r0 = (u32)f2bf(acc[0]) | ((u32)f2bf(acc[1]) << 16);
    u32 r1 = (u32)f2bf(acc[2]) | ((u32)f2bf(acc[3]) << 16);
    u32 r2 = (u32)f2bf(acc[4]) | ((u32)f2bf(acc[5]) << 16);
    u32 r3 = (u32)f2bf(acc[6]) | ((u32)f2bf(acc[7]) << 16);
    ((uint4*)t)[n * 16 + lane16] = make_uint4(r0, r1, r2, r3);
}

// ---------------- fused 2-GEMM MLP (+ FC1 fusion on last layer) ----------------
// block = 256 (4 waves), 64 rows/block; wave computes 16 rows x 128 cols.
__global__ __launch_bounds__(256) void k_mlp(const u16* __restrict__ t,
                                             const u16* __restrict__ Wt,
                                             const float* __restrict__ b1,
                                             const float* __restrict__ b2,
                                             u16* __restrict__ h,
                                             const float* __restrict__ fc1_w,
                                             const float* __restrict__ fc1_b,
                                             float* __restrict__ y,
                                             int layer, int act, int fuse_fc1){
    __shared__ __align__(16) u16 u_lds[4][16][136];   // padded stride: 272B rows
    int tid  = threadIdx.x;
    int wid  = tid >> 6, lane = tid & 63;
    int l16  = lane & 15, kg = lane >> 4;
    int rbase = blockIdx.x * 64 + wid * 16;
    const u16* Wt1 = Wt + (size_t)(layer * 2) * 16384;
    const u16* Wt2 = Wt1 + 16384;

    // ---- GEMM1: U = T @ W1 ----
    f32x4 acc[8];
    for (int f = 0; f < 8; ++f) acc[f] = (f32x4){0.f, 0.f, 0.f, 0.f};
    int arow = rbase + l16;
    for (int ks = 0; ks < 4; ++ks){
        int k0 = ks * 32 + kg * 8;
        short8 afrag = *(const short8*)(t + (size_t)arow * 128 + k0);
        for (int f = 0; f < 8; ++f){
            short8 bfrag = *(const short8*)(Wt1 + (f * 16 + l16) * 128 + k0);
            acc[f] = __builtin_amdgcn_mfma_f32_16x16x32_bf16(afrag, bfrag, acc[f], 0, 0, 0);
        }
    }
    // epilogue 1: +b1, leaky, to LDS (A-operand layout for GEMM2)
    for (int f = 0; f < 8; ++f){
        int col = f * 16 + l16;
        float bv = b1[layer * 128 + col];
        for (int j = 0; j < 4; ++j){
            float v = lk(acc[f][j] + bv);
            u_lds[wid][kg * 4 + j][col] = f2bf(v);
        }
    }
    __syncthreads();

    // ---- GEMM2: H = U @ W2 ----
    f32x4 acc2[8];
    for (int f = 0; f < 8; ++f) acc2[f] = (f32x4){0.f, 0.f, 0.f, 0.f};
    for (int ks = 0; ks < 4; ++ks){
        int k0 = ks * 32 + kg * 8;
        short8 afrag = *(const short8*)(&u_lds[wid][l16][k0]);
        for (int f = 0; f < 8; ++f){
            short8 bfrag = *(const short8*)(Wt2 + (f * 16 + l16) * 128 + k0);
            acc2[f] = __builtin_amdgcn_mfma_f32_16x16x32_bf16(afrag, bfrag, acc2[f], 0, 0, 0);
        }
    }

    if (fuse_fc1){
        // y[n] = sum_c leaky(acc2[c]+b2[c]) * fc1_w[c] + fc1_b  (no h write)
        float part[4] = {0.f, 0.f, 0.f, 0.f};
        for (int f = 0; f < 8; ++f){
            int col = f * 16 + l16;
            float bv = b2[layer * 128 + col];
            float wv = fc1_w[col];
            for (int j = 0; j < 4; ++j)
                part[j] += lk(acc2[f][j] + bv) * wv;
        }
        // reduce across the 16 lanes of this row group (xor within quarter-wave)
        for (int off = 8; off; off >>= 1)
            for (int j = 0; j < 4; ++j)
                part[j] += __shfl_xor(part[j], off, 64);
        if (l16 == 0){
            float fb = fc1_b[0];
            for (int j = 0; j < 4; ++j)
                y[rbase + kg * 4 + j] = part[j] + fb;
        }
    } else {
        for (int f = 0; f < 8; ++f){
            int col = f * 16 + l16;
            float bv = b2[layer * 128 + col];
            for (int j = 0; j < 4; ++j){
                float v = acc2[f][j] + bv;
                if (act) v = lk(v);
                h[(size_t)(rbase + kg * 4 + j) * 128 + col] = f2bf(v);
            }
        }
    }
}

// ---------------- FC2 + log_softmax ----------------
__global__ void k_fc2(const float* __restrict__ y, const float* __restrict__ fc2_w,
                      const float* __restrict__ fc2_b, float* __restrict__ out){
    int b = blockIdx.x, tid = threadIdx.x;
    float a0 = 0.f, a1 = 0.f;
    for (int j = tid; j < 1024; j += 256){
        float v = lk(y[b * 1024 + j]);
        a0 += v * fc2_w[j];
        a1 += v * fc2_w[1024 + j];
    }
    for (int off = 32; off; off >>= 1){
        a0 += __shfl_xor(a0, off, 64);
        a1 += __shfl_xor(a1, off, 64);
    }
    __shared__ float s0[4], s1[4];
    int wid = tid >> 6, lane = tid & 63;
    if (lane == 0){ s0[wid] = a0; s1[wid] = a1; }
    __syncthreads();
    if (tid == 0){
        float l0 = s0[0] + s0[1] + s0[2] + s0[3] + fc2_b[0];
        float l1 = s1[0] + s1[1] + s1[2] + s1[3] + fc2_b[1];
        float m = fmaxf(l0, l1);
        float lse = m + logf(expf(l0 - m) + expf(l1 - m));
        out[b * 2 + 0] = l0 - lse;
        out[b * 2 + 1] = l1 - lse;
    }
}

extern "C" void kernel_launch(void* const* d_in, const int* in_sizes, int n_in,
                              void* d_out, int out_size, void* d_ws, size_t ws_size,
                              hipStream_t stream){
    (void)in_sizes; (void)n_in; (void)out_size; (void)ws_size;
    const float* x     = (const float*)d_in[0];
    const float* W1    = (const float*)d_in[1];
    const float* b1    = (const float*)d_in[2];
    const float* W2    = (const float*)d_in[3];
    const float* b2    = (const float*)d_in[4];
    const float* fc1_w = (const float*)d_in[5];
    const float* fc1_b = (const float*)d_in[6];
    const float* fc2_w = (const float*)d_in[7];
    const float* fc2_b = (const float*)d_in[8];
    const int*   edges = (const int*)d_in[9];
    const int*   esrc  = edges;
    const int*   edst  = edges + NE;

    char* w = (char*)d_ws;
    u16* h   = (u16*)w;           w += (size_t)NTOT * CDIM * 2;        // 16 MB
    u16* t   = (u16*)w;           w += (size_t)NTOT * CDIM * 2;        // 16 MB
    u16* Wt  = (u16*)w;           w += (size_t)NLAYER * 2 * CDIM * CDIM * 2; // 256 KB
    float* y = (float*)w;         w += (size_t)NTOT * 4;               // 256 KB
    int* cnt = (int*)w;           w += (size_t)NTOT * 4;               // 256 KB
    u16* csrp = (u16*)w;          w += (size_t)NTOT * PAD * 2;         // 8 MB

    hipMemsetAsync(cnt, 0, (size_t)NTOT * 4, stream);
    k_cast_x<<<4096, 256, 0, stream>>>(x, h);
    k_conv_w<<<512, 256, 0, stream>>>(W1, W2, Wt);
    k_fillp <<<1024, 256, 0, stream>>>(esrc, edst, cnt, csrp);

    for (int l = 0; l < NLAYER; ++l){
        k_agg<<<4096, 256, 0, stream>>>(h, cnt, csrp, t);
        k_mlp<<<1024, 256, 0, stream>>>(t, Wt, b1, b2, h, fc1_w, fc1_b, y,
                                        l, (l < NLAYER - 1) ? 1 : 0,
                                        (l == NLAYER - 1) ? 1 : 0);
    }
    k_fc2<<<NGRAPH, 256, 0, stream>>>(y, fc2_w, fc2_b, (float*)d_out);
}